// Round 4
// baseline (1335.893 us; speedup 1.0000x reference)
//
#include <hip/hip_runtime.h>
#include <stdint.h>

// NCA step v4: LDS overlay (16.4 KB -> 8 blocks/CU, one residency round),
// granule-XOR-swizzled r1, B-fragment-order pre-packed weights.
// B=8, C=20, H=W=256, HID=128, K_in=60 (pad 64), steps=4.

#define Bsz 8
#define Cn  20
#define Hn  256
#define Wn  256
#define HW  (Hn*Wn)

typedef float  f32x4  __attribute__((ext_vector_type(4)));
typedef __bf16 bf16x8 __attribute__((ext_vector_type(8)));
typedef __bf16 bf16x4 __attribute__((ext_vector_type(4)));
typedef short  s16x8  __attribute__((ext_vector_type(8)));

// Threefry-2x32, 20 rounds (verified r1: matches jax threefry_partitionable).
__device__ __host__ __forceinline__ void tf2x32(uint32_t k0, uint32_t k1,
                                                uint32_t x0, uint32_t x1,
                                                uint32_t& o0, uint32_t& o1) {
  uint32_t ks2 = k0 ^ k1 ^ 0x1BD11BDAu;
  x0 += k0; x1 += k1;
#define TFR(r) { x0 += x1; x1 = (x1 << (r)) | (x1 >> (32 - (r))); x1 ^= x0; }
  TFR(13) TFR(15) TFR(26) TFR(6)
  x0 += k1;  x1 += ks2 + 1u;
  TFR(17) TFR(29) TFR(16) TFR(24)
  x0 += ks2; x1 += k0 + 2u;
  TFR(13) TFR(15) TFR(26) TFR(6)
  x0 += k0;  x1 += k1 + 3u;
  TFR(17) TFR(29) TFR(16) TFR(24)
  x0 += k1;  x1 += ks2 + 4u;
  TFR(13) TFR(15) TFR(26) TFR(6)
  x0 += ks2; x1 += k0 + 5u;
#undef TFR
  o0 = x0; o1 = x1;
}

__device__ __forceinline__ f32x4 mfma16(bf16x8 a, bf16x8 b, f32x4 c) {
  return __builtin_amdgcn_mfma_f32_16x16x32_bf16(
      __builtin_bit_cast(s16x8, a), __builtin_bit_cast(s16x8, b), c, 0, 0, 0);
}

// Pack weights into MFMA B-fragment lane order so in-kernel loads are one
// coalesced 16B/lane dwordx4 per fragment.
// W1p[((ch*2+nt)*2+kb)*64 + l][8]: j = ch*32+nt*16+(l&15), k = kb*32+(l>>4)*8+e.
// W2p[(ch*2+nt2)*64 + l][8]:      cc = nt2*16+(l&15),     k = ch*32+(l>>4)*8+e.
__global__ void pack_weights(const float* __restrict__ W1, const float* __restrict__ W2,
                             __bf16* __restrict__ W1p, __bf16* __restrict__ W2p) {
  int t = blockIdx.x * 256 + threadIdx.x;
  for (int i = t; i < 128 * 64; i += gridDim.x * 256) {
    int e = i & 7, l = (i >> 3) & 63, kb = (i >> 9) & 1, nt = (i >> 10) & 1, ch = i >> 11;
    int j = ch * 32 + nt * 16 + (l & 15);
    int k = kb * 32 + (l >> 4) * 8 + e;
    W1p[i] = (k < 60) ? (__bf16)W1[j * 60 + k] : (__bf16)0.f;
  }
  for (int i = t; i < 8 * 64 * 8; i += gridDim.x * 256) {
    int e = i & 7, l = (i >> 3) & 63, nt2 = (i >> 9) & 1, ch = i >> 10;
    int cc = nt2 * 16 + (l & 15);
    int k = ch * 32 + (l >> 4) * 8 + e;
    W2p[i] = (cc < 17) ? (__bf16)W2[(cc + 3) * 128 + k] : (__bf16)0.f;
  }
}

template <bool PRE>
__global__ __launch_bounds__(256, 8) void nca_step(
    const float* __restrict__ xin, float* __restrict__ xout,
    const float* __restrict__ wf1, const float* __restrict__ wf2,
    const float* __restrict__ W1, const float* __restrict__ b1,
    const float* __restrict__ W2,
    const __bf16* __restrict__ W1b, const __bf16* __restrict__ W2b,
    uint32_t ka, uint32_t kb_key) {

  // One 16384-B region, overlaid in time (barrier-separated):
  //   phase 1-3: xt  = halo tile [324 px][24 ch] bf16 (15552 B)
  //   phase 5+ : r1  = [256 rows][32 cols] bf16, granule-XOR swizzle
  //              (granule g' = g ^ ((row>>1)&3); 16B-aligned, <=2-way banks)
  __shared__ __align__(16) __bf16 smem[256 * 32];
  __bf16* xt = smem;
  __bf16* r1 = smem;

  const int tid = threadIdx.x;

  // XCD swizzle: round-robin dispatch -> XCD k handles batch image k.
  const int lin = (blockIdx.z * 16 + blockIdx.y) * 16 + blockIdx.x;
  const int swzb = (lin & 7) * 256 + (lin >> 3);
  const int b  = swzb >> 8;
  const int by = ((swzb >> 4) & 15) * 16;
  const int bx = (swzb & 15) * 16;

  const float* __restrict__ xb = xin + (size_t)b * Cn * HW;

  // ---- Phase 1: stage 18x18 halo (reflect) as bf16, channel-interleaved ----
#pragma unroll
  for (int s = 0; s < 2; ++s) {
    int p = tid + s * 256;
    if (p < 324) {
      int ly = p / 18, lx = p - ly * 18;
      int gy = by - 1 + ly; gy = (gy < 0) ? -gy : ((gy >= Hn) ? 2 * Hn - 2 - gy : gy);
      int gx = bx - 1 + lx; gx = (gx < 0) ? -gx : ((gx >= Wn) ? 2 * Wn - 2 - gx : gx);
      const float* sp = xb + (size_t)gy * Wn + gx;
      bf16x8 q0, q1; bf16x4 q2;
#pragma unroll
      for (int c = 0; c < 8; ++c)  q0[c] = (__bf16)sp[(size_t)c * HW];
#pragma unroll
      for (int c = 0; c < 8; ++c)  q1[c] = (__bf16)sp[(size_t)(c + 8) * HW];
#pragma unroll
      for (int c = 0; c < 4; ++c)  q2[c] = (__bf16)sp[(size_t)(c + 16) * HW];
      __bf16* wp = xt + p * 24;
      *(bf16x8*)(wp)      = q0;
      *(bf16x8*)(wp + 8)  = q1;
      *(bf16x4*)(wp + 16) = q2;
    }
  }
  __syncthreads();

  // ---- Phase 2: depthwise conv (fp32 math, bf16 taps) ----
  const int ty = tid >> 4, tx = tid & 15;
  float a1[Cn], a2[Cn];
#pragma unroll
  for (int c = 0; c < Cn; ++c) { a1[c] = 0.f; a2[c] = 0.f; }
  bf16x8 id0, id1; bf16x4 id2;  // center tap = identity part of perc

#pragma unroll
  for (int ky = 0; ky < 3; ++ky)
#pragma unroll
    for (int kx = 0; kx < 3; ++kx) {
      const __bf16* tp = xt + ((ty + ky) * 18 + tx + kx) * 24;
      bf16x8 t0 = *(const bf16x8*)(tp);
      bf16x8 t1 = *(const bf16x8*)(tp + 8);
      bf16x4 t2 = *(const bf16x4*)(tp + 16);
      if (ky == 1 && kx == 1) { id0 = t0; id1 = t1; id2 = t2; }
      const int tap = ky * 3 + kx;
#pragma unroll
      for (int c = 0; c < 8; ++c) {
        float v = (float)t0[c];
        a1[c] = fmaf(wf1[c * 9 + tap], v, a1[c]);
        a2[c] = fmaf(wf2[c * 9 + tap], v, a2[c]);
      }
#pragma unroll
      for (int c = 0; c < 8; ++c) {
        float v = (float)t1[c];
        a1[c + 8] = fmaf(wf1[(c + 8) * 9 + tap], v, a1[c + 8]);
        a2[c + 8] = fmaf(wf2[(c + 8) * 9 + tap], v, a2[c + 8]);
      }
#pragma unroll
      for (int c = 0; c < 4; ++c) {
        float v = (float)t2[c];
        a1[c + 16] = fmaf(wf1[(c + 16) * 9 + tap], v, a1[c + 16]);
        a2[c + 16] = fmaf(wf2[(c + 16) * 9 + tap], v, a2[c + 16]);
      }
    }
  __syncthreads();  // all xt reads done -> safe to overlay r1

  // ---- Phase 3: pack perc -> r1 (k-chunks of 32), load A-fragments ----
  const int l = tid & 63, w = tid >> 6;
  const int g4 = l >> 4, c16 = l & 15;
  const int rowbase = w * 64;
  const int myswz = (tid >> 1) & 3;

  bf16x8 af[4][2];
#pragma unroll
  for (int kb = 0; kb < 2; ++kb) {
#pragma unroll
    for (int g2 = 0; g2 < 4; ++g2) {
      bf16x8 pk;
#pragma unroll
      for (int e = 0; e < 8; ++e) {
        const int k = kb * 32 + g2 * 8 + e;
        __bf16 v;
        if      (k < 8)  v = id0[k];
        else if (k < 16) v = id1[k - 8];
        else if (k < 20) v = id2[k - 16];
        else if (k < 40) v = (__bf16)a1[k - 20];
        else if (k < 60) v = (__bf16)a2[k - 40];
        else             v = (__bf16)0.f;
        pk[e] = v;
      }
      *(bf16x8*)(r1 + tid * 32 + ((g2 ^ myswz) * 8)) = pk;
    }
    // same-wave LDS ops are in-order; all 64 lanes' writes precede these reads
#pragma unroll
    for (int mt = 0; mt < 4; ++mt) {
      int row = rowbase + mt * 16 + c16;
      af[mt][kb] = *(const bf16x8*)(r1 + row * 32 + ((g4 ^ ((row >> 1) & 3)) * 8));
    }
  }

  // ---- GEMM chunks: per 32 j's: GEMM1 -> H chunk (LDS) -> GEMM2 partial ----
  const f32x4 zero4 = {0.f, 0.f, 0.f, 0.f};
  f32x4 acc2[4][2];
#pragma unroll
  for (int mt = 0; mt < 4; ++mt) { acc2[mt][0] = zero4; acc2[mt][1] = zero4; }

  const bf16x8* w1v = (const bf16x8*)W1b;
  const bf16x8* w2v = (const bf16x8*)W2b;

  for (int ch = 0; ch < 4; ++ch) {
#pragma unroll
    for (int nt = 0; nt < 2; ++nt) {
      const int j = ch * 32 + nt * 16 + c16;
      bf16x8 bw0, bw1;
      if constexpr (PRE) {
        bw0 = w1v[((ch * 2 + nt) * 2 + 0) * 64 + l];
        bw1 = w1v[((ch * 2 + nt) * 2 + 1) * 64 + l];
      } else {
        const float* rp = W1 + j * 60;
#pragma unroll
        for (int kb = 0; kb < 2; ++kb) {
          int ks = kb * 32 + g4 * 8;
          f32x4 lo = *(const f32x4*)(rp + ks);
          int ks2 = (ks == 56) ? 52 : ks + 4;
          f32x4 hi = *(const f32x4*)(rp + ks2);
          hi = (ks == 56) ? zero4 : hi;
          bf16x8 pk;
#pragma unroll
          for (int e = 0; e < 4; ++e) { pk[e] = (__bf16)lo[e]; pk[e + 4] = (__bf16)hi[e]; }
          if (kb == 0) bw0 = pk; else bw1 = pk;
        }
      }
      f32x4 a[4];
#pragma unroll
      for (int mt = 0; mt < 4; ++mt) {
        a[mt] = mfma16(af[mt][0], bw0, zero4);
        a[mt] = mfma16(af[mt][1], bw1, a[mt]);
      }
      const float bias = b1[j];
#pragma unroll
      for (int mt = 0; mt < 4; ++mt)
#pragma unroll
        for (int r = 0; r < 4; ++r) {
          float hv = fmaxf(a[mt][r] + bias, 0.f);
          int row = rowbase + mt * 16 + g4 * 4 + r;
          int col = nt * 16 + c16;
          r1[row * 32 + (((col >> 3) ^ ((row >> 1) & 3)) * 8) + (col & 7)] = (__bf16)hv;
        }
    }
    // GEMM2 partial over this chunk's 32 j's
    bf16x8 ha[4];
#pragma unroll
    for (int mt = 0; mt < 4; ++mt) {
      int row = rowbase + mt * 16 + c16;
      ha[mt] = *(const bf16x8*)(r1 + row * 32 + ((g4 ^ ((row >> 1) & 3)) * 8));
    }
#pragma unroll
    for (int nt2 = 0; nt2 < 2; ++nt2) {
      const int cc = nt2 * 16 + c16;
      bf16x8 b2;
      if constexpr (PRE) {
        b2 = w2v[(ch * 2 + nt2) * 64 + l];
      } else {
        if (cc < 17) {
          const float* rp2 = W2 + (size_t)(cc + 3) * 128 + ch * 32 + g4 * 8;
          f32x4 lo = *(const f32x4*)(rp2);
          f32x4 hi = *(const f32x4*)(rp2 + 4);
#pragma unroll
          for (int e = 0; e < 4; ++e) { b2[e] = (__bf16)lo[e]; b2[e + 4] = (__bf16)hi[e]; }
        } else {
#pragma unroll
          for (int e = 0; e < 8; ++e) b2[e] = (__bf16)0.f;
        }
      }
#pragma unroll
      for (int mt = 0; mt < 4; ++mt)
        acc2[mt][nt2] = mfma16(ha[mt], b2, acc2[mt][nt2]);
    }
  }

  // ---- dx -> r1 (wave-private rows, cols 0..16) ----
#pragma unroll
  for (int mt = 0; mt < 4; ++mt)
#pragma unroll
    for (int nt2 = 0; nt2 < 2; ++nt2)
#pragma unroll
      for (int r = 0; r < 4; ++r) {
        int cc = nt2 * 16 + c16;
        if (cc < 17) {
          int row = rowbase + mt * 16 + g4 * 4 + r;
          r1[row * 32 + (((cc >> 3) ^ ((row >> 1) & 3)) * 8) + (cc & 7)] = (__bf16)acc2[mt][nt2][r];
        }
      }

  // fire mask (threefry, verified r1)
  const int gy = by + ty, gx = bx + tx;
  uint32_t y0, y1;
  tf2x32(ka, kb_key, 0u, (uint32_t)((b * Hn + gy) * Wn + gx), y0, y1);
  const float fire = ((y0 ^ y1) & 0x80000000u) ? 0.f : 1.f;

  float dxv[17];
#pragma unroll
  for (int q = 0; q < 3; ++q) {
    bf16x8 v = *(const bf16x8*)(r1 + tid * 32 + ((q ^ myswz) * 8));
#pragma unroll
    for (int e = 0; e < 8; ++e) {
      int idx = q * 8 + e;
      if (idx < 17) dxv[idx] = (float)v[e];
    }
  }

  const float* __restrict__ xp = xb + (size_t)gy * Wn + gx;
  float* __restrict__ op = xout + (size_t)b * Cn * HW + (size_t)gy * Wn + gx;
#pragma unroll
  for (int c = 0; c < 3; ++c)
    op[(size_t)c * HW] = xp[(size_t)c * HW];           // exact fp32 passthrough
#pragma unroll
  for (int c = 3; c < Cn; ++c)
    op[(size_t)c * HW] = xp[(size_t)c * HW] + dxv[c - 3] * fire;
}

extern "C" void kernel_launch(void* const* d_in, const int* in_sizes, int n_in,
                              void* d_out, int out_size, void* d_ws, size_t ws_size,
                              hipStream_t stream) {
  const float* x   = (const float*)d_in[0];
  const float* wf1 = (const float*)d_in[1];
  const float* wf2 = (const float*)d_in[2];
  const float* W1  = (const float*)d_in[3];
  const float* b1  = (const float*)d_in[4];
  const float* W2  = (const float*)d_in[5];
  const int steps = 4;

  float* out = (float*)d_out;
  float* ws0 = (float*)d_ws;                       // 41,943,040 B ping buffer
  const size_t PING = (size_t)Bsz * Cn * HW * 4;
  const size_t WNEED = PING + (128 * 64 + 8 * 64 * 8) * sizeof(__bf16);
  const bool pre = (ws_size >= WNEED);
  __bf16* W1p = pre ? (__bf16*)((char*)d_ws + PING) : nullptr;
  __bf16* W2p = pre ? W1p + 128 * 64 : nullptr;

  if (pre) pack_weights<<<8, 256, 0, stream>>>(W1, W2, W1p, W2p);

  dim3 grid(16, 16, Bsz);
  dim3 blk(256);

  const float* src = x;
  for (int s = 0; s < steps; ++s) {
    uint32_t ka, kb;
    tf2x32(0u, 42u, 0u, (uint32_t)s, ka, kb);      // fold_in(key(42), s)
    float* dst = (((steps - s) % 2) == 1) ? out : ws0;
    if (pre) nca_step<true ><<<grid, blk, 0, stream>>>(src, dst, wf1, wf2, W1, b1, W2, W1p, W2p, ka, kb);
    else     nca_step<false><<<grid, blk, 0, stream>>>(src, dst, wf1, wf2, W1, b1, W2, W1p, W2p, ka, kb);
    src = dst;
  }
}

// Round 5
// 348.410 us; speedup vs baseline: 3.8343x; 3.8343x over previous
//
#include <hip/hip_runtime.h>
#include <stdint.h>

// NCA step v5 = v4 (16.4 KB LDS overlay, swizzled r1, pre-packed B-frag
// weights) with launch_bounds reverted to (256,4): v4's (256,8) forced a
// 64-VGPR cap -> full scratch spill (FETCH 545MB). Natural alloc ~60 VGPR
// still allows 8 blocks/CU with 16.4 KB LDS.
// B=8, C=20, H=W=256, HID=128, K_in=60 (pad 64), steps=4.

#define Bsz 8
#define Cn  20
#define Hn  256
#define Wn  256
#define HW  (Hn*Wn)

typedef float  f32x4  __attribute__((ext_vector_type(4)));
typedef __bf16 bf16x8 __attribute__((ext_vector_type(8)));
typedef __bf16 bf16x4 __attribute__((ext_vector_type(4)));
typedef short  s16x8  __attribute__((ext_vector_type(8)));

// Threefry-2x32, 20 rounds (verified r1: matches jax threefry_partitionable).
__device__ __host__ __forceinline__ void tf2x32(uint32_t k0, uint32_t k1,
                                                uint32_t x0, uint32_t x1,
                                                uint32_t& o0, uint32_t& o1) {
  uint32_t ks2 = k0 ^ k1 ^ 0x1BD11BDAu;
  x0 += k0; x1 += k1;
#define TFR(r) { x0 += x1; x1 = (x1 << (r)) | (x1 >> (32 - (r))); x1 ^= x0; }
  TFR(13) TFR(15) TFR(26) TFR(6)
  x0 += k1;  x1 += ks2 + 1u;
  TFR(17) TFR(29) TFR(16) TFR(24)
  x0 += ks2; x1 += k0 + 2u;
  TFR(13) TFR(15) TFR(26) TFR(6)
  x0 += k0;  x1 += k1 + 3u;
  TFR(17) TFR(29) TFR(16) TFR(24)
  x0 += k1;  x1 += ks2 + 4u;
  TFR(13) TFR(15) TFR(26) TFR(6)
  x0 += ks2; x1 += k0 + 5u;
#undef TFR
  o0 = x0; o1 = x1;
}

__device__ __forceinline__ f32x4 mfma16(bf16x8 a, bf16x8 b, f32x4 c) {
  return __builtin_amdgcn_mfma_f32_16x16x32_bf16(
      __builtin_bit_cast(s16x8, a), __builtin_bit_cast(s16x8, b), c, 0, 0, 0);
}

// Pack weights into MFMA B-fragment lane order so in-kernel loads are one
// coalesced 16B/lane dwordx4 per fragment.
// W1p[((ch*2+nt)*2+kb)*64 + l][8]: j = ch*32+nt*16+(l&15), k = kb*32+(l>>4)*8+e.
// W2p[(ch*2+nt2)*64 + l][8]:      cc = nt2*16+(l&15),     k = ch*32+(l>>4)*8+e.
__global__ void pack_weights(const float* __restrict__ W1, const float* __restrict__ W2,
                             __bf16* __restrict__ W1p, __bf16* __restrict__ W2p) {
  int t = blockIdx.x * 256 + threadIdx.x;
  for (int i = t; i < 128 * 64; i += gridDim.x * 256) {
    int e = i & 7, l = (i >> 3) & 63, kb = (i >> 9) & 1, nt = (i >> 10) & 1, ch = i >> 11;
    int j = ch * 32 + nt * 16 + (l & 15);
    int k = kb * 32 + (l >> 4) * 8 + e;
    W1p[i] = (k < 60) ? (__bf16)W1[j * 60 + k] : (__bf16)0.f;
  }
  for (int i = t; i < 8 * 64 * 8; i += gridDim.x * 256) {
    int e = i & 7, l = (i >> 3) & 63, nt2 = (i >> 9) & 1, ch = i >> 10;
    int cc = nt2 * 16 + (l & 15);
    int k = ch * 32 + (l >> 4) * 8 + e;
    W2p[i] = (cc < 17) ? (__bf16)W2[(cc + 3) * 128 + k] : (__bf16)0.f;
  }
}

template <bool PRE>
__global__ __launch_bounds__(256, 4) void nca_step(
    const float* __restrict__ xin, float* __restrict__ xout,
    const float* __restrict__ wf1, const float* __restrict__ wf2,
    const float* __restrict__ W1, const float* __restrict__ b1,
    const float* __restrict__ W2,
    const __bf16* __restrict__ W1b, const __bf16* __restrict__ W2b,
    uint32_t ka, uint32_t kb_key) {

  // One 16384-B region, overlaid in time (barrier-separated):
  //   phase 1-2: xt = halo tile [324 px][24 ch] bf16 (15552 B)
  //   phase 3+ : r1 = [256 rows][32 cols] bf16, granule-XOR swizzle
  //              (granule g' = g ^ ((row>>1)&3); 16B-aligned, <=2-way banks)
  __shared__ __align__(16) __bf16 smem[256 * 32];
  __bf16* xt = smem;
  __bf16* r1 = smem;

  const int tid = threadIdx.x;

  // XCD swizzle: round-robin dispatch -> XCD k handles batch image k.
  const int lin = (blockIdx.z * 16 + blockIdx.y) * 16 + blockIdx.x;
  const int swzb = (lin & 7) * 256 + (lin >> 3);
  const int b  = swzb >> 8;
  const int by = ((swzb >> 4) & 15) * 16;
  const int bx = (swzb & 15) * 16;

  const float* __restrict__ xb = xin + (size_t)b * Cn * HW;

  // ---- Phase 1: stage 18x18 halo (reflect) as bf16, channel-interleaved ----
#pragma unroll
  for (int s = 0; s < 2; ++s) {
    int p = tid + s * 256;
    if (p < 324) {
      int ly = p / 18, lx = p - ly * 18;
      int gy = by - 1 + ly; gy = (gy < 0) ? -gy : ((gy >= Hn) ? 2 * Hn - 2 - gy : gy);
      int gx = bx - 1 + lx; gx = (gx < 0) ? -gx : ((gx >= Wn) ? 2 * Wn - 2 - gx : gx);
      const float* sp = xb + (size_t)gy * Wn + gx;
      bf16x8 q0, q1; bf16x4 q2;
#pragma unroll
      for (int c = 0; c < 8; ++c)  q0[c] = (__bf16)sp[(size_t)c * HW];
#pragma unroll
      for (int c = 0; c < 8; ++c)  q1[c] = (__bf16)sp[(size_t)(c + 8) * HW];
#pragma unroll
      for (int c = 0; c < 4; ++c)  q2[c] = (__bf16)sp[(size_t)(c + 16) * HW];
      __bf16* wp = xt + p * 24;
      *(bf16x8*)(wp)      = q0;
      *(bf16x8*)(wp + 8)  = q1;
      *(bf16x4*)(wp + 16) = q2;
    }
  }
  __syncthreads();

  // ---- Phase 2: depthwise conv (fp32 math, bf16 taps) ----
  const int ty = tid >> 4, tx = tid & 15;
  float a1[Cn], a2[Cn];
#pragma unroll
  for (int c = 0; c < Cn; ++c) { a1[c] = 0.f; a2[c] = 0.f; }
  bf16x8 id0, id1; bf16x4 id2;  // center tap = identity part of perc

#pragma unroll
  for (int ky = 0; ky < 3; ++ky)
#pragma unroll
    for (int kx = 0; kx < 3; ++kx) {
      const __bf16* tp = xt + ((ty + ky) * 18 + tx + kx) * 24;
      bf16x8 t0 = *(const bf16x8*)(tp);
      bf16x8 t1 = *(const bf16x8*)(tp + 8);
      bf16x4 t2 = *(const bf16x4*)(tp + 16);
      if (ky == 1 && kx == 1) { id0 = t0; id1 = t1; id2 = t2; }
      const int tap = ky * 3 + kx;
#pragma unroll
      for (int c = 0; c < 8; ++c) {
        float v = (float)t0[c];
        a1[c] = fmaf(wf1[c * 9 + tap], v, a1[c]);
        a2[c] = fmaf(wf2[c * 9 + tap], v, a2[c]);
      }
#pragma unroll
      for (int c = 0; c < 8; ++c) {
        float v = (float)t1[c];
        a1[c + 8] = fmaf(wf1[(c + 8) * 9 + tap], v, a1[c + 8]);
        a2[c + 8] = fmaf(wf2[(c + 8) * 9 + tap], v, a2[c + 8]);
      }
#pragma unroll
      for (int c = 0; c < 4; ++c) {
        float v = (float)t2[c];
        a1[c + 16] = fmaf(wf1[(c + 16) * 9 + tap], v, a1[c + 16]);
        a2[c + 16] = fmaf(wf2[(c + 16) * 9 + tap], v, a2[c + 16]);
      }
    }
  __syncthreads();  // all xt reads done -> safe to overlay r1

  // ---- Phase 3: pack perc -> r1 (k-chunks of 32), load A-fragments ----
  const int l = tid & 63, w = tid >> 6;
  const int g4 = l >> 4, c16 = l & 15;
  const int rowbase = w * 64;
  const int myswz = (tid >> 1) & 3;

  bf16x8 af[4][2];
#pragma unroll
  for (int kb = 0; kb < 2; ++kb) {
#pragma unroll
    for (int g2 = 0; g2 < 4; ++g2) {
      bf16x8 pk;
#pragma unroll
      for (int e = 0; e < 8; ++e) {
        const int k = kb * 32 + g2 * 8 + e;
        __bf16 v;
        if      (k < 8)  v = id0[k];
        else if (k < 16) v = id1[k - 8];
        else if (k < 20) v = id2[k - 16];
        else if (k < 40) v = (__bf16)a1[k - 20];
        else if (k < 60) v = (__bf16)a2[k - 40];
        else             v = (__bf16)0.f;
        pk[e] = v;
      }
      *(bf16x8*)(r1 + tid * 32 + ((g2 ^ myswz) * 8)) = pk;
    }
    // same-wave LDS ops are in-order; all 64 lanes' writes precede these reads
#pragma unroll
    for (int mt = 0; mt < 4; ++mt) {
      int row = rowbase + mt * 16 + c16;
      af[mt][kb] = *(const bf16x8*)(r1 + row * 32 + ((g4 ^ ((row >> 1) & 3)) * 8));
    }
  }

  // ---- GEMM chunks: per 32 j's: GEMM1 -> H chunk (LDS) -> GEMM2 partial ----
  const f32x4 zero4 = {0.f, 0.f, 0.f, 0.f};
  f32x4 acc2[4][2];
#pragma unroll
  for (int mt = 0; mt < 4; ++mt) { acc2[mt][0] = zero4; acc2[mt][1] = zero4; }

  const bf16x8* w1v = (const bf16x8*)W1b;
  const bf16x8* w2v = (const bf16x8*)W2b;

  for (int ch = 0; ch < 4; ++ch) {
#pragma unroll
    for (int nt = 0; nt < 2; ++nt) {
      const int j = ch * 32 + nt * 16 + c16;
      bf16x8 bw0, bw1;
      if constexpr (PRE) {
        bw0 = w1v[((ch * 2 + nt) * 2 + 0) * 64 + l];
        bw1 = w1v[((ch * 2 + nt) * 2 + 1) * 64 + l];
      } else {
        const float* rp = W1 + j * 60;
#pragma unroll
        for (int kb = 0; kb < 2; ++kb) {
          int ks = kb * 32 + g4 * 8;
          f32x4 lo = *(const f32x4*)(rp + ks);
          int ks2 = (ks == 56) ? 52 : ks + 4;
          f32x4 hi = *(const f32x4*)(rp + ks2);
          hi = (ks == 56) ? zero4 : hi;
          bf16x8 pk;
#pragma unroll
          for (int e = 0; e < 4; ++e) { pk[e] = (__bf16)lo[e]; pk[e + 4] = (__bf16)hi[e]; }
          if (kb == 0) bw0 = pk; else bw1 = pk;
        }
      }
      f32x4 a[4];
#pragma unroll
      for (int mt = 0; mt < 4; ++mt) {
        a[mt] = mfma16(af[mt][0], bw0, zero4);
        a[mt] = mfma16(af[mt][1], bw1, a[mt]);
      }
      const float bias = b1[j];
#pragma unroll
      for (int mt = 0; mt < 4; ++mt)
#pragma unroll
        for (int r = 0; r < 4; ++r) {
          float hv = fmaxf(a[mt][r] + bias, 0.f);
          int row = rowbase + mt * 16 + g4 * 4 + r;
          int col = nt * 16 + c16;
          r1[row * 32 + (((col >> 3) ^ ((row >> 1) & 3)) * 8) + (col & 7)] = (__bf16)hv;
        }
    }
    // GEMM2 partial over this chunk's 32 j's
    bf16x8 ha[4];
#pragma unroll
    for (int mt = 0; mt < 4; ++mt) {
      int row = rowbase + mt * 16 + c16;
      ha[mt] = *(const bf16x8*)(r1 + row * 32 + ((g4 ^ ((row >> 1) & 3)) * 8));
    }
#pragma unroll
    for (int nt2 = 0; nt2 < 2; ++nt2) {
      const int cc = nt2 * 16 + c16;
      bf16x8 b2;
      if constexpr (PRE) {
        b2 = w2v[(ch * 2 + nt2) * 64 + l];
      } else {
        if (cc < 17) {
          const float* rp2 = W2 + (size_t)(cc + 3) * 128 + ch * 32 + g4 * 8;
          f32x4 lo = *(const f32x4*)(rp2);
          f32x4 hi = *(const f32x4*)(rp2 + 4);
#pragma unroll
          for (int e = 0; e < 4; ++e) { b2[e] = (__bf16)lo[e]; b2[e + 4] = (__bf16)hi[e]; }
        } else {
#pragma unroll
          for (int e = 0; e < 8; ++e) b2[e] = (__bf16)0.f;
        }
      }
#pragma unroll
      for (int mt = 0; mt < 4; ++mt)
        acc2[mt][nt2] = mfma16(ha[mt], b2, acc2[mt][nt2]);
    }
  }

  // ---- dx -> r1 (wave-private rows, cols 0..16) ----
#pragma unroll
  for (int mt = 0; mt < 4; ++mt)
#pragma unroll
    for (int nt2 = 0; nt2 < 2; ++nt2)
#pragma unroll
      for (int r = 0; r < 4; ++r) {
        int cc = nt2 * 16 + c16;
        if (cc < 17) {
          int row = rowbase + mt * 16 + g4 * 4 + r;
          r1[row * 32 + (((cc >> 3) ^ ((row >> 1) & 3)) * 8) + (cc & 7)] = (__bf16)acc2[mt][nt2][r];
        }
      }

  // fire mask (threefry, verified r1)
  const int gy = by + ty, gx = bx + tx;
  uint32_t y0, y1;
  tf2x32(ka, kb_key, 0u, (uint32_t)((b * Hn + gy) * Wn + gx), y0, y1);
  const float fire = ((y0 ^ y1) & 0x80000000u) ? 0.f : 1.f;

  float dxv[17];
#pragma unroll
  for (int q = 0; q < 3; ++q) {
    bf16x8 v = *(const bf16x8*)(r1 + tid * 32 + ((q ^ myswz) * 8));
#pragma unroll
    for (int e = 0; e < 8; ++e) {
      int idx = q * 8 + e;
      if (idx < 17) dxv[idx] = (float)v[e];
    }
  }

  const float* __restrict__ xp = xb + (size_t)gy * Wn + gx;
  float* __restrict__ op = xout + (size_t)b * Cn * HW + (size_t)gy * Wn + gx;
#pragma unroll
  for (int c = 0; c < 3; ++c)
    op[(size_t)c * HW] = xp[(size_t)c * HW];           // exact fp32 passthrough
#pragma unroll
  for (int c = 3; c < Cn; ++c)
    op[(size_t)c * HW] = xp[(size_t)c * HW] + dxv[c - 3] * fire;
}

extern "C" void kernel_launch(void* const* d_in, const int* in_sizes, int n_in,
                              void* d_out, int out_size, void* d_ws, size_t ws_size,
                              hipStream_t stream) {
  const float* x   = (const float*)d_in[0];
  const float* wf1 = (const float*)d_in[1];
  const float* wf2 = (const float*)d_in[2];
  const float* W1  = (const float*)d_in[3];
  const float* b1  = (const float*)d_in[4];
  const float* W2  = (const float*)d_in[5];
  const int steps = 4;

  float* out = (float*)d_out;
  float* ws0 = (float*)d_ws;                       // 41,943,040 B ping buffer
  const size_t PING = (size_t)Bsz * Cn * HW * 4;
  const size_t WNEED = PING + (128 * 64 + 8 * 64 * 8) * sizeof(__bf16);
  const bool pre = (ws_size >= WNEED);
  __bf16* W1p = pre ? (__bf16*)((char*)d_ws + PING) : nullptr;
  __bf16* W2p = pre ? W1p + 128 * 64 : nullptr;

  if (pre) pack_weights<<<8, 256, 0, stream>>>(W1, W2, W1p, W2p);

  dim3 grid(16, 16, Bsz);
  dim3 blk(256);

  const float* src = x;
  for (int s = 0; s < steps; ++s) {
    uint32_t ka, kb;
    tf2x32(0u, 42u, 0u, (uint32_t)s, ka, kb);      // fold_in(key(42), s)
    float* dst = (((steps - s) % 2) == 1) ? out : ws0;
    if (pre) nca_step<true ><<<grid, blk, 0, stream>>>(src, dst, wf1, wf2, W1, b1, W2, W1p, W2p, ka, kb);
    else     nca_step<false><<<grid, blk, 0, stream>>>(src, dst, wf1, wf2, W1, b1, W2, W1p, W2p, ka, kb);
    src = dst;
  }
}

// Round 6
// 181.394 us; speedup vs baseline: 7.3646x; 1.9207x over previous
//
#include <hip/hip_runtime.h>
#include <stdint.h>

// NCA step v6: r3 structure (pitch-40 r1, no XOR swizzle) + swapped GEMM2
// (dx = W2·H^T, D maps straight to coalesced global writes, no dxl round
// trip) + ballot fire mask + fire computed in load shadow.
// B=8, C=20, H=W=256, HID=128, K_in=60 (pad 64), steps=4.

#define Bsz 8
#define Cn  20
#define Hn  256
#define Wn  256
#define HW  (Hn*Wn)

typedef float  f32x4  __attribute__((ext_vector_type(4)));
typedef __bf16 bf16x8 __attribute__((ext_vector_type(8)));
typedef __bf16 bf16x4 __attribute__((ext_vector_type(4)));
typedef short  s16x8  __attribute__((ext_vector_type(8)));

// Threefry-2x32, 20 rounds (verified r1: matches jax threefry_partitionable).
__device__ __host__ __forceinline__ void tf2x32(uint32_t k0, uint32_t k1,
                                                uint32_t x0, uint32_t x1,
                                                uint32_t& o0, uint32_t& o1) {
  uint32_t ks2 = k0 ^ k1 ^ 0x1BD11BDAu;
  x0 += k0; x1 += k1;
#define TFR(r) { x0 += x1; x1 = (x1 << (r)) | (x1 >> (32 - (r))); x1 ^= x0; }
  TFR(13) TFR(15) TFR(26) TFR(6)
  x0 += k1;  x1 += ks2 + 1u;
  TFR(17) TFR(29) TFR(16) TFR(24)
  x0 += ks2; x1 += k0 + 2u;
  TFR(13) TFR(15) TFR(26) TFR(6)
  x0 += k0;  x1 += k1 + 3u;
  TFR(17) TFR(29) TFR(16) TFR(24)
  x0 += k1;  x1 += ks2 + 4u;
  TFR(13) TFR(15) TFR(26) TFR(6)
  x0 += ks2; x1 += k0 + 5u;
#undef TFR
  o0 = x0; o1 = x1;
}

__device__ __forceinline__ f32x4 mfma16(bf16x8 a, bf16x8 b, f32x4 c) {
  return __builtin_amdgcn_mfma_f32_16x16x32_bf16(
      __builtin_bit_cast(s16x8, a), __builtin_bit_cast(s16x8, b), c, 0, 0, 0);
}

// W1p: GEMM1 B-fragments. i = (((ch*2+nt)*2+kb)*64 + l)*8 + e:
//   j = ch*32+nt*16+(l&15), k = kb*32+(l>>4)*8+e  -> W1[j][k] (k<60 else 0)
// W2p: GEMM2 A-fragments (SWAPPED: A = W2, m = channel). i = ((mt*4+kb)*64+l)*8+e:
//   ch = mt*16+(l&15), j = kb*32+(l>>4)*8+e -> W2[ch][j] for 3<=ch<20 else 0
__global__ void pack_weights(const float* __restrict__ W1, const float* __restrict__ W2,
                             __bf16* __restrict__ W1p, __bf16* __restrict__ W2p) {
  int t = blockIdx.x * 256 + threadIdx.x;
  for (int i = t; i < 128 * 64; i += gridDim.x * 256) {
    int e = i & 7, l = (i >> 3) & 63, kb = (i >> 9) & 1, nt = (i >> 10) & 1, ch = i >> 11;
    int j = ch * 32 + nt * 16 + (l & 15);
    int k = kb * 32 + (l >> 4) * 8 + e;
    W1p[i] = (k < 60) ? (__bf16)W1[j * 60 + k] : (__bf16)0.f;
  }
  for (int i = t; i < 2 * 4 * 64 * 8; i += gridDim.x * 256) {
    int e = i & 7, l = (i >> 3) & 63, kb = (i >> 9) & 3, mt = (i >> 11) & 1;
    int ch = mt * 16 + (l & 15);
    int j  = kb * 32 + (l >> 4) * 8 + e;
    W2p[i] = (ch >= 3 && ch < Cn) ? (__bf16)W2[ch * 128 + j] : (__bf16)0.f;
  }
}

template <bool PRE>
__global__ __launch_bounds__(256, 4) void nca_step(
    const float* __restrict__ xin, float* __restrict__ xout,
    const float* __restrict__ wf1, const float* __restrict__ wf2,
    const float* __restrict__ W1, const float* __restrict__ b1,
    const float* __restrict__ W2,
    const __bf16* __restrict__ W1b, const __bf16* __restrict__ W2b,
    uint32_t ka, uint32_t kb_key) {

  // One 20480-B region, time-overlaid (barrier-separated):
  //   phase 1-2: xt = halo tile [324 px][24 ch] bf16 (15552 B)
  //   phase 3+ : r1 = [256 rows][40 cols] bf16 (plain pitch, ~2-way banks)
  __shared__ __align__(16) __bf16 smem[256 * 40];
  __bf16* xt = smem;
  __bf16* r1 = smem;

  const int tid = threadIdx.x;

  // XCD swizzle: round-robin dispatch -> XCD k handles batch image k.
  const int lin = (blockIdx.z * 16 + blockIdx.y) * 16 + blockIdx.x;
  const int swzb = (lin & 7) * 256 + (lin >> 3);
  const int b  = swzb >> 8;
  const int by = ((swzb >> 4) & 15) * 16;
  const int bx = (swzb & 15) * 16;

  const float* __restrict__ xb = xin + (size_t)b * Cn * HW;
  const int ty = tid >> 4, tx = tid & 15;

  // ---- Phase 1: stage 18x18 halo (reflect) as bf16, channel-interleaved ----
#pragma unroll
  for (int s = 0; s < 2; ++s) {
    int p = tid + s * 256;
    if (p < 324) {
      int ly = p / 18, lx = p - ly * 18;
      int gy = by - 1 + ly; gy = (gy < 0) ? -gy : ((gy >= Hn) ? 2 * Hn - 2 - gy : gy);
      int gx = bx - 1 + lx; gx = (gx < 0) ? -gx : ((gx >= Wn) ? 2 * Wn - 2 - gx : gx);
      const float* sp = xb + (size_t)gy * Wn + gx;
      bf16x8 q0, q1; bf16x4 q2;
#pragma unroll
      for (int c = 0; c < 8; ++c)  q0[c] = (__bf16)sp[(size_t)c * HW];
#pragma unroll
      for (int c = 0; c < 8; ++c)  q1[c] = (__bf16)sp[(size_t)(c + 8) * HW];
#pragma unroll
      for (int c = 0; c < 4; ++c)  q2[c] = (__bf16)sp[(size_t)(c + 16) * HW];
      __bf16* wp = xt + p * 24;
      *(bf16x8*)(wp)      = q0;
      *(bf16x8*)(wp + 8)  = q1;
      *(bf16x4*)(wp + 16) = q2;
    }
  }

  // Fire mask in the load shadow (threefry verified r1); one ballot per wave.
  uint32_t y0, y1;
  tf2x32(ka, kb_key, 0u, (uint32_t)((b * Hn + by + ty) * Wn + bx + tx), y0, y1);
  const unsigned long long fmask = __ballot(((y0 ^ y1) & 0x80000000u) == 0u);

  __syncthreads();

  // ---- Phase 2: depthwise conv (fp32 math, bf16 taps) ----
  float a1[Cn], a2[Cn];
#pragma unroll
  for (int c = 0; c < Cn; ++c) { a1[c] = 0.f; a2[c] = 0.f; }
  bf16x8 id0, id1; bf16x4 id2;  // center tap = identity part of perc

#pragma unroll
  for (int ky = 0; ky < 3; ++ky)
#pragma unroll
    for (int kx = 0; kx < 3; ++kx) {
      const __bf16* tp = xt + ((ty + ky) * 18 + tx + kx) * 24;
      bf16x8 t0 = *(const bf16x8*)(tp);
      bf16x8 t1 = *(const bf16x8*)(tp + 8);
      bf16x4 t2 = *(const bf16x4*)(tp + 16);
      if (ky == 1 && kx == 1) { id0 = t0; id1 = t1; id2 = t2; }
      const int tap = ky * 3 + kx;
#pragma unroll
      for (int c = 0; c < 8; ++c) {
        float v = (float)t0[c];
        a1[c] = fmaf(wf1[c * 9 + tap], v, a1[c]);
        a2[c] = fmaf(wf2[c * 9 + tap], v, a2[c]);
      }
#pragma unroll
      for (int c = 0; c < 8; ++c) {
        float v = (float)t1[c];
        a1[c + 8] = fmaf(wf1[(c + 8) * 9 + tap], v, a1[c + 8]);
        a2[c + 8] = fmaf(wf2[(c + 8) * 9 + tap], v, a2[c + 8]);
      }
#pragma unroll
      for (int c = 0; c < 4; ++c) {
        float v = (float)t2[c];
        a1[c + 16] = fmaf(wf1[(c + 16) * 9 + tap], v, a1[c + 16]);
        a2[c + 16] = fmaf(wf2[(c + 16) * 9 + tap], v, a2[c + 16]);
      }
    }
  __syncthreads();  // all xt reads done -> safe to overlay r1

  // ---- Phase 3: perc -> r1 (time-shared 32-k chunks), load A-fragments ----
  const int l = tid & 63, w = tid >> 6;
  const int g4 = l >> 4, c16 = l & 15;
  const int rowbase = w * 64;

  bf16x8 af[4][2];
#pragma unroll
  for (int kb = 0; kb < 2; ++kb) {
#pragma unroll
    for (int g2 = 0; g2 < 4; ++g2) {
      bf16x8 pk;
#pragma unroll
      for (int e = 0; e < 8; ++e) {
        const int k = kb * 32 + g2 * 8 + e;
        __bf16 v;
        if      (k < 8)  v = id0[k];
        else if (k < 16) v = id1[k - 8];
        else if (k < 20) v = id2[k - 16];
        else if (k < 40) v = (__bf16)a1[k - 20];
        else if (k < 60) v = (__bf16)a2[k - 40];
        else             v = (__bf16)0.f;
        pk[e] = v;
      }
      *(bf16x8*)(r1 + tid * 40 + g2 * 8) = pk;
    }
    // same-wave LDS ops are in-order; all 64 lanes' writes precede these reads
#pragma unroll
    for (int mt = 0; mt < 4; ++mt) {
      int row = rowbase + mt * 16 + c16;
      af[mt][kb] = *(const bf16x8*)(r1 + row * 40 + g4 * 8);
    }
  }

  // ---- GEMM chunks: per 32 j's: GEMM1 -> H chunk (LDS) -> GEMM2 (swapped) ----
  const f32x4 zero4 = {0.f, 0.f, 0.f, 0.f};
  f32x4 acc2[2][4];   // [mt: ch 0..15 / 16..31][nt: 16-px groups]
#pragma unroll
  for (int mt = 0; mt < 2; ++mt)
#pragma unroll
    for (int nt = 0; nt < 4; ++nt) acc2[mt][nt] = zero4;

  const bf16x8* w1v = (const bf16x8*)W1b;
  const bf16x8* w2v = (const bf16x8*)W2b;

  for (int ch4 = 0; ch4 < 4; ++ch4) {
    // GEMM1 chunk: H[256 x 32j] = perc @ W1_chunk^T
#pragma unroll
    for (int nt = 0; nt < 2; ++nt) {
      const int j = ch4 * 32 + nt * 16 + c16;
      bf16x8 bw0, bw1;
      if constexpr (PRE) {
        bw0 = w1v[((ch4 * 2 + nt) * 2 + 0) * 64 + l];
        bw1 = w1v[((ch4 * 2 + nt) * 2 + 1) * 64 + l];
      } else {
        const float* rp = W1 + j * 60;
#pragma unroll
        for (int kb = 0; kb < 2; ++kb) {
          int ks = kb * 32 + g4 * 8;
          f32x4 lo = *(const f32x4*)(rp + ks);
          int ks2 = (ks == 56) ? 52 : ks + 4;
          f32x4 hi = *(const f32x4*)(rp + ks2);
          hi = (ks == 56) ? zero4 : hi;
          bf16x8 pk;
#pragma unroll
          for (int e = 0; e < 4; ++e) { pk[e] = (__bf16)lo[e]; pk[e + 4] = (__bf16)hi[e]; }
          if (kb == 0) bw0 = pk; else bw1 = pk;
        }
      }
      f32x4 a[4];
#pragma unroll
      for (int mt = 0; mt < 4; ++mt) {
        a[mt] = mfma16(af[mt][0], bw0, zero4);
        a[mt] = mfma16(af[mt][1], bw1, a[mt]);
      }
      const float bias = b1[j];
#pragma unroll
      for (int mt = 0; mt < 4; ++mt)
#pragma unroll
        for (int r = 0; r < 4; ++r) {
          float hv = fmaxf(a[mt][r] + bias, 0.f);
          int row = rowbase + mt * 16 + g4 * 4 + r;
          r1[row * 40 + nt * 16 + c16] = (__bf16)hv;
        }
    }
    // GEMM2 (swapped): dx[ch][px] += W2_chunk @ H_chunk^T
    bf16x8 wa[2];
#pragma unroll
    for (int mt = 0; mt < 2; ++mt) {
      if constexpr (PRE) {
        wa[mt] = w2v[(mt * 4 + ch4) * 64 + l];
      } else {
        const int chl = mt * 16 + c16;
        bf16x8 pk;
        if (chl >= 3 && chl < Cn) {
          const float* rp2 = W2 + (size_t)chl * 128 + ch4 * 32 + g4 * 8;
          f32x4 lo = *(const f32x4*)(rp2);
          f32x4 hi = *(const f32x4*)(rp2 + 4);
#pragma unroll
          for (int e = 0; e < 4; ++e) { pk[e] = (__bf16)lo[e]; pk[e + 4] = (__bf16)hi[e]; }
        } else {
#pragma unroll
          for (int e = 0; e < 8; ++e) pk[e] = (__bf16)0.f;
        }
        wa[mt] = pk;
      }
    }
#pragma unroll
    for (int nt = 0; nt < 4; ++nt) {
      // B-fragment: lane holds H[px = rowbase+nt*16+(l&15)][j-octet (l>>4)*8]
      bf16x8 hb = *(const bf16x8*)(r1 + (rowbase + nt * 16 + c16) * 40 + g4 * 8);
#pragma unroll
      for (int mt = 0; mt < 2; ++mt)
        acc2[mt][nt] = mfma16(wa[mt], hb, acc2[mt][nt]);
    }
  }

  // ---- Epilogue: D2 lane layout = (px = l&15 within nt-group, ch = g4*4+r).
  // out[ch][px] = x[ch][px] + dx*fire; W2 rows <3 and >=20 are zero-padded,
  // so image channels pass through automatically.
  float* __restrict__ ob = xout + (size_t)b * Cn * HW;
#pragma unroll
  for (int nt = 0; nt < 4; ++nt) {
    const int pxl = rowbase + nt * 16 + c16;              // pixel 0..255 in tile
    const int gy = by + (pxl >> 4), gx = bx + (pxl & 15);
    const size_t pix = (size_t)gy * Wn + gx;
    const float fire = ((fmask >> (nt * 16 + c16)) & 1ull) ? 1.f : 0.f;
#pragma unroll
    for (int mt = 0; mt < 2; ++mt)
#pragma unroll
      for (int r = 0; r < 4; ++r) {
        const int ch = mt * 16 + g4 * 4 + r;
        if (ch < Cn) {
          const size_t off = (size_t)ch * HW + pix;
          ob[off] = xb[off] + acc2[mt][nt][r] * fire;
        }
      }
  }
}

extern "C" void kernel_launch(void* const* d_in, const int* in_sizes, int n_in,
                              void* d_out, int out_size, void* d_ws, size_t ws_size,
                              hipStream_t stream) {
  const float* x   = (const float*)d_in[0];
  const float* wf1 = (const float*)d_in[1];
  const float* wf2 = (const float*)d_in[2];
  const float* W1  = (const float*)d_in[3];
  const float* b1  = (const float*)d_in[4];
  const float* W2  = (const float*)d_in[5];
  const int steps = 4;

  float* out = (float*)d_out;
  float* ws0 = (float*)d_ws;                       // 41,943,040 B ping buffer
  const size_t PING = (size_t)Bsz * Cn * HW * 4;
  const size_t WNEED = PING + (128 * 64 + 2 * 4 * 64 * 8) * sizeof(__bf16);
  const bool pre = (ws_size >= WNEED);
  __bf16* W1p = pre ? (__bf16*)((char*)d_ws + PING) : nullptr;
  __bf16* W2p = pre ? W1p + 128 * 64 : nullptr;

  if (pre) pack_weights<<<8, 256, 0, stream>>>(W1, W2, W1p, W2p);

  dim3 grid(16, 16, Bsz);
  dim3 blk(256);

  const float* src = x;
  for (int s = 0; s < steps; ++s) {
    uint32_t ka, kb;
    tf2x32(0u, 42u, 0u, (uint32_t)s, ka, kb);      // fold_in(key(42), s)
    float* dst = (((steps - s) % 2) == 1) ? out : ws0;
    if (pre) nca_step<true ><<<grid, blk, 0, stream>>>(src, dst, wf1, wf2, W1, b1, W2, W1p, W2p, ka, kb);
    else     nca_step<false><<<grid, blk, 0, stream>>>(src, dst, wf1, wf2, W1, b1, W2, W1p, W2p, ka, kb);
    src = dst;
  }
}